// Round 5
// baseline (748.874 us; speedup 1.0000x reference)
//
#include <hip/hip_runtime.h>

typedef __attribute__((ext_vector_type(8))) short short8;
typedef __attribute__((ext_vector_type(4))) float f32x4;

// bf16 weight workspace layout (element offsets) — all N padded to x4 16-tiles
#define OFF_WX 0         // [256][512]
#define OFF_W1 131072    // [128][512]  (real 100x512)
#define OFF_W2 196608    // [128][128]  (real 100x100)
#define OFF_W3 212992    // [128][128]  (real 100x100)
#define OFF_W4 229376    // [ 64][128]  (real  50x100)
#define OFF_W5 237568    // [256][ 64]  (real 256x50)
#define W_TOTAL 253952   // bf16 elements
#define TR 32            // timestep rows per block (fused fallback)

// ---- pipeline-path workspace byte offsets ----
#define PB_HID   524288u            // fp32 [256][256]
#define PB_A1    786432u            // bf16 [131072][128]
#define PB_LX    34340864u          // bf16 [131072][256] (sig(lx), then gate in place)
#define PB_NEED  101449728u

static __device__ __forceinline__ unsigned short f2bf(float f) {
    unsigned int u = __builtin_bit_cast(unsigned int, f);
    unsigned int r = (u + 0x7fffu + ((u >> 16) & 1u)) >> 16;
    return (unsigned short)r;
}
static __device__ __forceinline__ float bf2f(unsigned short h) {
    unsigned int u = ((unsigned int)h) << 16;
    return __builtin_bit_cast(float, u);
}
// sigmoid via fast exp + fast rcp
static __device__ __forceinline__ float sigf(float z) {
    return __builtin_amdgcn_rcpf(1.f + __expf(-z));
}
// swizzled bf16 store into a [rows][128] activation tile (16B-chunk xor-swizzle, r&15)
static __device__ __forceinline__ void stA(unsigned short* dst, int r, int c, float v) {
    dst[(r << 7) + (((c >> 3) ^ (r & 15)) << 3) + (c & 7)] = f2bf(v);
}
// swizzled element index into a [32][256] bf16 tile
static __device__ __forceinline__ int idxG(int r, int c) {
    return (r << 8) + (((c >> 3) ^ (r & 15)) << 3) + (c & 7);
}

#define MFMA(a, bfr, acc) __builtin_amdgcn_mfma_f32_16x16x32_bf16((a), (bfr), (acc), 0, 0, 0)

// ---------------- prep: fp32 weights -> padded bf16 in ws; zero hidden accum ----
__global__ __launch_bounds__(256) void prep_kernel(
    const float* __restrict__ wx, const float* __restrict__ wm1,
    const float* __restrict__ wm2, const float* __restrict__ wm3,
    const float* __restrict__ wm4, const float* __restrict__ wm5,
    unsigned short* __restrict__ wb, float* __restrict__ hid)
{
    const int stride = gridDim.x * blockDim.x;
    for (int idx = blockIdx.x * blockDim.x + threadIdx.x; idx < W_TOTAL; idx += stride) {
        float v;
        if (idx < OFF_W1) {
            v = wx[idx];                                      // exact 256x512
        } else if (idx < OFF_W2) {
            int j = idx - OFF_W1; int n = j >> 9, k = j & 511;
            v = (n < 100) ? wm1[n * 512 + k] : 0.f;
        } else if (idx < OFF_W3) {
            int j = idx - OFF_W2; int n = j >> 7, k = j & 127;
            v = (n < 100 && k < 100) ? wm2[n * 100 + k] : 0.f;
        } else if (idx < OFF_W4) {
            int j = idx - OFF_W3; int n = j >> 7, k = j & 127;
            v = (n < 100 && k < 100) ? wm3[n * 100 + k] : 0.f;
        } else if (idx < OFF_W5) {
            int j = idx - OFF_W4; int n = j >> 7, k = j & 127;
            v = (n < 50 && k < 100) ? wm4[n * 100 + k] : 0.f;
        } else {
            int j = idx - OFF_W5; int n = j >> 6, k = j & 63;
            v = (k < 50) ? wm5[n * 50 + k] : 0.f;
        }
        wb[idx] = f2bf(v);
    }
    for (int idx = blockIdx.x * blockDim.x + threadIdx.x; idx < 65536; idx += stride)
        hid[idx] = 0.f;
}

// ================= PIPELINE PATH =================================================
// pass1: rows = t*256+b (contiguous in x). Block = 32 rows, 4 waves.
// wave w: m1 n-tiles {w, w+4} (cols 0..127), lx n-tiles {w,w+4,w+8,w+12} (0..255).
// One barrier (after staging). Writes A1 [R][128] bf16 and sig(lx+bx) [R][256] bf16.
__global__ __launch_bounds__(256, 4) void pass1_kernel(
    const float* __restrict__ x, const float* __restrict__ b1,
    const float* __restrict__ bxv, const unsigned short* __restrict__ wb,
    unsigned short* __restrict__ A1g, unsigned short* __restrict__ Lxg)
{
    __shared__ __align__(16) unsigned short Xs[32 * 512];   // swizzled x tile (32 KB)

    const int tid  = threadIdx.x;
    const int w    = tid >> 6, lane = tid & 63;
    const int l15  = lane & 15;
    const int rb   = (lane >> 4) << 2;
    const int kp   = (lane >> 4) << 3;
    const size_t r0 = (size_t)blockIdx.x * 32;

    // ---- stage: 32 contiguous rows of x (64 KB), fully coalesced
    {
        const float4* xb = (const float4*)(x + r0 * 512);
        float4 xr[16];
#pragma unroll
        for (int it = 0; it < 16; it++)
            xr[it] = xb[it * 256 + tid];
#pragma unroll
        for (int it = 0; it < 16; it++) {
            const int e = (it * 256 + tid) << 2;       // element index in [32][512]
            const int m = e >> 9, c = e & 511;
            unsigned int p0 = (unsigned int)f2bf(xr[it].x) | ((unsigned int)f2bf(xr[it].y) << 16);
            unsigned int p1 = (unsigned int)f2bf(xr[it].z) | ((unsigned int)f2bf(xr[it].w) << 16);
            *(uint2*)&Xs[(m << 9) + (((c >> 3) ^ (m & 15)) << 3) + (c & 7)] = make_uint2(p0, p1);
        }
    }
    __syncthreads();

    // ---- K=512 GEMM: 12 accumulators/wave (proven round-0 shape)
    f32x4 am1[2][2], alx[4][2];
#pragma unroll
    for (int i = 0; i < 2; i++) { am1[i][0] = {0,0,0,0}; am1[i][1] = {0,0,0,0}; }
#pragma unroll
    for (int i = 0; i < 4; i++) { alx[i][0] = {0,0,0,0}; alx[i][1] = {0,0,0,0}; }
    {
        const unsigned short* W1p = wb + OFF_W1 + l15 * 512 + kp;
        const unsigned short* WXp = wb + OFF_WX + l15 * 512 + kp;
#pragma unroll 4
        for (int k0 = 0; k0 < 512; k0 += 32) {
            const int kb = (k0 >> 3) + (lane >> 4);
            const int xo = (kb ^ l15) << 3;
            short8 af0 = *(const short8*)(Xs + (l15 << 9) + xo);
            short8 af1 = *(const short8*)(Xs + ((16 + l15) << 9) + xo);
#pragma unroll
            for (int i = 0; i < 2; i++) {
                short8 bf = *(const short8*)(W1p + ((w + 4 * i) << 13) + k0);   // *16*512
                am1[i][0] = MFMA(af0, bf, am1[i][0]);
                am1[i][1] = MFMA(af1, bf, am1[i][1]);
            }
#pragma unroll
            for (int i = 0; i < 4; i++) {
                short8 bf = *(const short8*)(WXp + ((w + 4 * i) << 13) + k0);
                alx[i][0] = MFMA(af0, bf, alx[i][0]);
                alx[i][1] = MFMA(af1, bf, alx[i][1]);
            }
        }
    }
    // ---- epilogues -> global (bf16 scalar; 16-lane groups = 32B segments)
#pragma unroll
    for (int i = 0; i < 2; i++) {
        const int c = (w + 4 * i) * 16 + l15;
        const bool ok = (c < 100);
        const float bb = ok ? b1[c] : 0.f;
#pragma unroll
        for (int mt = 0; mt < 2; mt++)
#pragma unroll
            for (int q = 0; q < 4; q++) {
                const int r = mt * 16 + rb + q;
                A1g[(r0 + r) * 128 + c] = f2bf(ok ? fmaxf(am1[i][mt][q] + bb, 0.f) : 0.f);
            }
    }
#pragma unroll
    for (int i = 0; i < 4; i++) {
        const int c = (w + 4 * i) * 16 + l15;
        const float bb = bxv[c];
#pragma unroll
        for (int mt = 0; mt < 2; mt++)
#pragma unroll
            for (int q = 0; q < 4; q++) {
                const int r = mt * 16 + rb + q;
                Lxg[(r0 + r) * 256 + c] = f2bf(sigf(alx[i][mt][q] + bb));
            }
    }
}

// tail: m2->m3->m4->m5+gate with ZERO barriers. Block = 4 waves; each wave owns
// 16 rows end-to-end, staging inter-stage activations through a wave-private
// 4KB LDS slice (same-wave lgkmcnt ordering only). Weights stay L2-hot.
__global__ __launch_bounds__(256, 6) void tail_kernel(
    const float* __restrict__ b2, const float* __restrict__ b3,
    const float* __restrict__ b4, const float* __restrict__ b5,
    const unsigned short* __restrict__ wb,
    const unsigned short* __restrict__ A1g, unsigned short* __restrict__ Lxg)
{
    __shared__ __align__(16) unsigned short Sc[4][16 * 128];   // 16 KB total

    const int tid  = threadIdx.x;
    const int w    = tid >> 6, lane = tid & 63;
    const int l15  = lane & 15;
    const int rb   = (lane >> 4) << 2;
    const int kp   = (lane >> 4) << 3;
    unsigned short* Ws = Sc[w];
    const size_t gr = (size_t)blockIdx.x * 64 + w * 16;        // this wave's 16 rows

    // ---- m2: A-frags straight from global A1 (no LDS staging needed)
    {
        short8 af[4];
#pragma unroll
        for (int kk = 0; kk < 4; kk++)
            af[kk] = *(const short8*)(A1g + (gr + l15) * 128 + kk * 32 + kp);
        f32x4 acc[8];
#pragma unroll
        for (int n = 0; n < 8; n++) acc[n] = {0,0,0,0};
#pragma unroll
        for (int kk = 0; kk < 4; kk++)
#pragma unroll
            for (int n = 0; n < 8; n++) {
                short8 bf = *(const short8*)(wb + OFF_W2 + (n * 16 + l15) * 128 + kk * 32 + kp);
                acc[n] = MFMA(af[kk], bf, acc[n]);
            }
#pragma unroll
        for (int n = 0; n < 8; n++) {
            const int c = n * 16 + l15;
            const bool ok = (c < 100);
            const float bb = ok ? b2[c] : 0.f;
#pragma unroll
            for (int q = 0; q < 4; q++)
                stA(Ws, rb + q, c, ok ? fmaxf(acc[n][q] + bb, 0.f) : 0.f);
        }
    }
    // ---- m3: LDS -> LDS (read all frags first, then overwrite)
    {
        short8 af[4];
#pragma unroll
        for (int kk = 0; kk < 4; kk++)
            af[kk] = *(const short8*)(Ws + (l15 << 7) + ((((kk << 2) + (lane >> 4)) ^ l15) << 3));
        f32x4 acc[8];
#pragma unroll
        for (int n = 0; n < 8; n++) acc[n] = {0,0,0,0};
#pragma unroll
        for (int kk = 0; kk < 4; kk++)
#pragma unroll
            for (int n = 0; n < 8; n++) {
                short8 bf = *(const short8*)(wb + OFF_W3 + (n * 16 + l15) * 128 + kk * 32 + kp);
                acc[n] = MFMA(af[kk], bf, acc[n]);
            }
#pragma unroll
        for (int n = 0; n < 8; n++) {
            const int c = n * 16 + l15;
            const bool ok = (c < 100);
            const float bb = ok ? b3[c] : 0.f;
#pragma unroll
            for (int q = 0; q < 4; q++)
                stA(Ws, rb + q, c, ok ? fmaxf(acc[n][q] + bb, 0.f) : 0.f);
        }
    }
    // ---- m4: N=64 (real 50)
    {
        short8 af[4];
#pragma unroll
        for (int kk = 0; kk < 4; kk++)
            af[kk] = *(const short8*)(Ws + (l15 << 7) + ((((kk << 2) + (lane >> 4)) ^ l15) << 3));
        f32x4 acc[4];
#pragma unroll
        for (int n = 0; n < 4; n++) acc[n] = {0,0,0,0};
#pragma unroll
        for (int kk = 0; kk < 4; kk++)
#pragma unroll
            for (int n = 0; n < 4; n++) {
                short8 bf = *(const short8*)(wb + OFF_W4 + (n * 16 + l15) * 128 + kk * 32 + kp);
                acc[n] = MFMA(af[kk], bf, acc[n]);
            }
#pragma unroll
        for (int n = 0; n < 4; n++) {
            const int c = n * 16 + l15;
            const bool ok = (c < 50);
            const float bb = ok ? b4[c] : 0.f;
#pragma unroll
            for (int q = 0; q < 4; q++)
                stA(Ws, rb + q, c, ok ? fmaxf(acc[n][q] + bb, 0.f) : 0.f);
        }
    }
    // ---- m5 (K=64, N=256 in two halves of 8 n-tiles); gate in place over Lxg
    {
        short8 af[2];
#pragma unroll
        for (int kk = 0; kk < 2; kk++)
            af[kk] = *(const short8*)(Ws + (l15 << 7) + ((((kk << 2) + (lane >> 4)) ^ l15) << 3));
#pragma unroll
        for (int h = 0; h < 2; h++) {
            f32x4 acc[8];
#pragma unroll
            for (int n = 0; n < 8; n++) acc[n] = {0,0,0,0};
#pragma unroll
            for (int kk = 0; kk < 2; kk++)
#pragma unroll
                for (int n = 0; n < 8; n++) {
                    const int ng = h * 8 + n;
                    short8 bf = *(const short8*)(wb + OFF_W5 + (ng * 16 + l15) * 64 + kk * 32 + kp);
                    acc[n] = MFMA(af[kk], bf, acc[n]);
                }
#pragma unroll
            for (int n = 0; n < 8; n++) {
                const int c = (h * 8 + n) * 16 + l15;
                const float bb5 = b5[c];
#pragma unroll
                for (int q = 0; q < 4; q++) {
                    const size_t ga = (gr + rb + q) * 256 + c;
                    const float g = sigf(acc[n][q] + bb5) * bf2f(Lxg[ga]);
                    Lxg[ga] = f2bf(g);       // each (row,c) owned by one lane
                }
            }
        }
    }
}

// reduce: hid[b][j] = sum_t gate[t*256+b][(j+t+1)&255]; 4-way t-split per batch
__global__ __launch_bounds__(256) void reduce_kernel(
    const unsigned short* __restrict__ gate, float* __restrict__ hid)
{
    const int b  = blockIdx.x >> 2;
    const int tq = blockIdx.x & 3;
    const int j  = threadIdx.x;
    float s = 0.f;
#pragma unroll 8
    for (int it = 0; it < 128; it++) {
        const int t = tq * 128 + it;
        const int c = (j + t + 1) & 255;
        s += bf2f(gate[((size_t)(t << 8) + b) * 256 + c]);
    }
    atomicAdd(hid + b * 256 + j, s);
}

// ================= FUSED FALLBACK (round-3 kernel, proven passing) ===============
__global__ __launch_bounds__(512, 8) void srnn_main(
    const float* __restrict__ x,
    const float* __restrict__ b1, const float* __restrict__ b2,
    const float* __restrict__ b3, const float* __restrict__ b4,
    const float* __restrict__ b5, const float* __restrict__ bx,
    const unsigned short* __restrict__ wb, float* __restrict__ hid)
{
    __shared__ __align__(16) unsigned short Xs[TR * 512];
    __shared__ __align__(16) unsigned short A1[TR * 128];
    unsigned short* A2  = Xs;
    unsigned short* Lxs = Xs + 4096;

    const int tid  = threadIdx.x;
    const int w    = tid >> 6, lane = tid & 63;
    const int blk  = blockIdx.x;
    const int b    = blk >> 4;
    const int t0   = (blk & 15) << 5;
    const int l15  = lane & 15;
    const int rb   = (lane >> 4) << 2;
    const int kp   = (lane >> 4) << 3;

    {
        const int m0 = tid >> 7;
        const int c4 = tid & 127;
        const float* xbase = x + ((size_t)(t0 + m0) * 256 + b) * 512 + (c4 << 2);
        float4 xr[8];
#pragma unroll
        for (int it = 0; it < 8; it++)
            xr[it] = *(const float4*)(xbase + (size_t)it * 524288);
        const int blk8 = c4 >> 1, halfoff = (c4 & 1) << 2;
#pragma unroll
        for (int it = 0; it < 8; it++) {
            const int m = m0 + 4 * it;
            unsigned int p0 = (unsigned int)f2bf(xr[it].x) | ((unsigned int)f2bf(xr[it].y) << 16);
            unsigned int p1 = (unsigned int)f2bf(xr[it].z) | ((unsigned int)f2bf(xr[it].w) << 16);
            *(uint2*)&Xs[(m << 9) + ((blk8 ^ (m & 15)) << 3) + halfoff] = make_uint2(p0, p1);
        }
    }
    __syncthreads();

    f32x4 am1[2], alx[2][2];
    am1[0] = {0,0,0,0}; am1[1] = {0,0,0,0};
#pragma unroll
    for (int i = 0; i < 2; i++) { alx[i][0] = {0,0,0,0}; alx[i][1] = {0,0,0,0}; }
    {
        const unsigned short* W1r  = wb + OFF_W1 + (w * 16 + l15) * 512 + kp;
        const unsigned short* WXr0 = wb + OFF_WX + (w * 16 + l15) * 512 + kp;
        const unsigned short* WXr1 = wb + OFF_WX + ((w + 8) * 16 + l15) * 512 + kp;
#pragma unroll 4
        for (int k0 = 0; k0 < 512; k0 += 32) {
            const int kb = (k0 >> 3) + (lane >> 4);
            const int xo = (kb ^ l15) << 3;
            short8 af0 = *(const short8*)(Xs + (l15 << 9) + xo);
            short8 af1 = *(const short8*)(Xs + ((16 + l15) << 9) + xo);
            short8 b0  = *(const short8*)(W1r + k0);
            short8 bx0 = *(const short8*)(WXr0 + k0);
            short8 bx1 = *(const short8*)(WXr1 + k0);
            am1[0]    = MFMA(af0, b0,  am1[0]);
            am1[1]    = MFMA(af1, b0,  am1[1]);
            alx[0][0] = MFMA(af0, bx0, alx[0][0]);
            alx[0][1] = MFMA(af1, bx0, alx[0][1]);
            alx[1][0] = MFMA(af0, bx1, alx[1][0]);
            alx[1][1] = MFMA(af1, bx1, alx[1][1]);
        }
        const int c = w * 16 + l15;
        const bool ok = (c < 100);
        const float bb = ok ? b1[c] : 0.f;
#pragma unroll
        for (int mt = 0; mt < 2; mt++)
#pragma unroll
            for (int q = 0; q < 4; q++)
                stA(A1, mt * 16 + rb + q, c, ok ? fmaxf(am1[mt][q] + bb, 0.f) : 0.f);
    }
    __syncthreads();

    {
#pragma unroll
        for (int i = 0; i < 2; i++) {
            const int c = (w + 8 * i) * 16 + l15;
            const float bbx = bx[c];
#pragma unroll
            for (int mt = 0; mt < 2; mt++)
#pragma unroll
                for (int q = 0; q < 4; q++) {
                    const int r = mt * 16 + rb + q;
                    Lxs[idxG(r, c)] = f2bf(sigf(alx[i][mt][q] + bbx));
                }
        }
    }

    auto stage23 = [&](const unsigned short* As, const unsigned short* Wg,
                       const float* __restrict__ bias, unsigned short* Ad) {
        f32x4 acc[2];
        acc[0] = {0,0,0,0}; acc[1] = {0,0,0,0};
        const unsigned short* Wr = Wg + (w * 16 + l15) * 128 + kp;
#pragma unroll
        for (int k0 = 0; k0 < 128; k0 += 32) {
            const int kb = (k0 >> 3) + (lane >> 4);
            const int xo = (kb ^ l15) << 3;
            short8 af0 = *(const short8*)(As + (l15 << 7) + xo);
            short8 af1 = *(const short8*)(As + ((16 + l15) << 7) + xo);
            short8 bf  = *(const short8*)(Wr + k0);
            acc[0] = MFMA(af0, bf, acc[0]);
            acc[1] = MFMA(af1, bf, acc[1]);
        }
        const int c = w * 16 + l15;
        const bool ok = (c < 100);
        const float bb = ok ? bias[c] : 0.f;
#pragma unroll
        for (int mt = 0; mt < 2; mt++)
#pragma unroll
            for (int q = 0; q < 4; q++)
                stA(Ad, mt * 16 + rb + q, c, ok ? fmaxf(acc[mt][q] + bb, 0.f) : 0.f);
    };
    stage23(A1, wb + OFF_W2, b2, A2);
    __syncthreads();
    stage23(A2, wb + OFF_W3, b3, A1);
    __syncthreads();

    {
        const int nt = w >> 1, mtl = w & 1;
        f32x4 acc = {0,0,0,0};
        const unsigned short* Wr = wb + OFF_W4 + (nt * 16 + l15) * 128 + kp;
        const int rbase = mtl * 16 + l15;
        const int rxo = rbase & 15;
#pragma unroll
        for (int k0 = 0; k0 < 128; k0 += 32) {
            const int kb = (k0 >> 3) + (lane >> 4);
            short8 af = *(const short8*)(A1 + (rbase << 7) + ((kb ^ rxo) << 3));
            short8 bf = *(const short8*)(Wr + k0);
            acc = MFMA(af, bf, acc);
        }
        const int c = nt * 16 + l15;
        const bool ok = (c < 50);
        const float bb = ok ? b4[c] : 0.f;
#pragma unroll
        for (int q = 0; q < 4; q++)
            stA(A2, mtl * 16 + rb + q, c, ok ? fmaxf(acc[q] + bb, 0.f) : 0.f);
    }
    __syncthreads();

    {
        f32x4 a5[2][2];
#pragma unroll
        for (int i = 0; i < 2; i++) { a5[i][0] = {0,0,0,0}; a5[i][1] = {0,0,0,0}; }
        const unsigned short* W5r0 = wb + OFF_W5 + (w * 16 + l15) * 64 + kp;
        const unsigned short* W5r1 = wb + OFF_W5 + ((w + 8) * 16 + l15) * 64 + kp;
#pragma unroll
        for (int k0 = 0; k0 < 64; k0 += 32) {
            const int kb = (k0 >> 3) + (lane >> 4);
            const int xo = (kb ^ l15) << 3;
            short8 af0 = *(const short8*)(A2 + (l15 << 7) + xo);
            short8 af1 = *(const short8*)(A2 + ((16 + l15) << 7) + xo);
            short8 bf0 = *(const short8*)(W5r0 + k0);
            short8 bf1 = *(const short8*)(W5r1 + k0);
            a5[0][0] = MFMA(af0, bf0, a5[0][0]);
            a5[0][1] = MFMA(af1, bf0, a5[0][1]);
            a5[1][0] = MFMA(af0, bf1, a5[1][0]);
            a5[1][1] = MFMA(af1, bf1, a5[1][1]);
        }
#pragma unroll
        for (int i = 0; i < 2; i++) {
            const int c = (w + 8 * i) * 16 + l15;
            const float bb5 = b5[c];
#pragma unroll
            for (int mt = 0; mt < 2; mt++)
#pragma unroll
                for (int q = 0; q < 4; q++) {
                    const int r = mt * 16 + rb + q;
                    const int ix = idxG(r, c);
                    const float g = sigf(a5[i][mt][q] + bb5) * bf2f(Lxs[ix]);
                    Lxs[ix] = f2bf(g);
                }
        }
    }
    __syncthreads();

    {
        const int j    = tid & 255;
        const int half = tid >> 8;
        const int base = (j + t0 + 1) & 255;
        float ph = 0.f;
#pragma unroll
        for (int mm = 0; mm < 16; mm++) {
            const int m  = half * 16 + mm;
            const int cm = (base + m) & 255;
            ph += bf2f(Lxs[idxG(m, cm)]);
        }
        atomicAdd(hid + b * 256 + j, ph);
    }
}

// ---------------- output: out = hidden @ wo^T + bo ; also emit hidden ----------
__global__ __launch_bounds__(256) void out_kernel(
    const float* __restrict__ hid, const float* __restrict__ wo,
    const float* __restrict__ bo, float* __restrict__ out)
{
    __shared__ __align__(16) float hrow[256];
    const int b = blockIdx.x, o = threadIdx.x;
    float h = hid[b * 256 + o];
    hrow[o] = h;
    out[65536 + b * 256 + o] = h;          // second output: hidden
    __syncthreads();
    const float4* wrow = (const float4*)(wo + o * 256);
    float s = bo[o];
#pragma unroll 8
    for (int k4 = 0; k4 < 64; k4++) {
        float4 w = wrow[k4];
        float4 hh = *(const float4*)&hrow[k4 * 4];
        s += hh.x * w.x + hh.y * w.y + hh.z * w.z + hh.w * w.w;
    }
    out[b * 256 + o] = s;
}

extern "C" void kernel_launch(void* const* d_in, const int* in_sizes, int n_in,
                              void* d_out, int out_size, void* d_ws, size_t ws_size,
                              hipStream_t stream)
{
    (void)in_sizes; (void)n_in; (void)out_size;
    const float* x   = (const float*)d_in[0];
    const float* wm1 = (const float*)d_in[1];
    const float* bm1 = (const float*)d_in[2];
    const float* wm2 = (const float*)d_in[3];
    const float* bm2 = (const float*)d_in[4];
    const float* wm3 = (const float*)d_in[5];
    const float* bm3 = (const float*)d_in[6];
    const float* wm4 = (const float*)d_in[7];
    const float* bm4 = (const float*)d_in[8];
    const float* wm5 = (const float*)d_in[9];
    const float* bm5 = (const float*)d_in[10];
    const float* wx  = (const float*)d_in[11];
    const float* bx  = (const float*)d_in[12];
    const float* wo  = (const float*)d_in[13];
    const float* bo  = (const float*)d_in[14];
    float* out = (float*)d_out;

    unsigned short* wb = (unsigned short*)d_ws;

    if (ws_size >= (size_t)PB_NEED) {
        // ---- pipeline path
        float*          hid = (float*)((char*)d_ws + PB_HID);
        unsigned short* A1g = (unsigned short*)((char*)d_ws + PB_A1);
        unsigned short* Lxg = (unsigned short*)((char*)d_ws + PB_LX);
        prep_kernel<<<512, 256, 0, stream>>>(wx, wm1, wm2, wm3, wm4, wm5, wb, hid);
        pass1_kernel<<<4096, 256, 0, stream>>>(x, bm1, bx, wb, A1g, Lxg);
        tail_kernel<<<2048, 256, 0, stream>>>(bm2, bm3, bm4, bm5, wb, A1g, Lxg);
        reduce_kernel<<<1024, 256, 0, stream>>>(Lxg, hid);
        out_kernel<<<256, 256, 0, stream>>>(hid, wo, bo, out);
    } else {
        // ---- fused fallback (round-3 proven)
        float* hid = (float*)((char*)d_ws + (size_t)W_TOTAL * 2);
        prep_kernel<<<512, 256, 0, stream>>>(wx, wm1, wm2, wm3, wm4, wm5, wb, hid);
        srnn_main<<<4096, 512, 0, stream>>>(x, bm1, bm2, bm3, bm4, bm5, bx, wb, hid);
        out_kernel<<<256, 256, 0, stream>>>(hid, wo, bo, out);
    }
}

// Round 6
// 598.283 us; speedup vs baseline: 1.2517x; 1.2517x over previous
//
#include <hip/hip_runtime.h>

typedef __attribute__((ext_vector_type(8))) short short8;
typedef __attribute__((ext_vector_type(4))) float f32x4;

// bf16 weight workspace layout (element offsets) — all N padded to x4 16-tiles
#define OFF_WX 0         // [256][512]
#define OFF_W1 131072    // [128][512]  (real 100x512)
#define OFF_W2 196608    // [128][128]  (real 100x100)
#define OFF_W3 212992    // [128][128]  (real 100x100)
#define OFF_W4 229376    // [ 64][128]  (real  50x100)
#define OFF_W5 237568    // [256][ 64]  (real 256x50)
#define W_TOTAL 253952   // bf16 elements
#define TR 32            // timestep rows per block

static __device__ __forceinline__ unsigned short f2bf(float f) {
    unsigned int u = __builtin_bit_cast(unsigned int, f);
    unsigned int r = (u + 0x7fffu + ((u >> 16) & 1u)) >> 16;
    return (unsigned short)r;
}
static __device__ __forceinline__ float bf2f(unsigned short h) {
    unsigned int u = ((unsigned int)h) << 16;
    return __builtin_bit_cast(float, u);
}
// sigmoid via fast exp + fast rcp
static __device__ __forceinline__ float sigf(float z) {
    return __builtin_amdgcn_rcpf(1.f + __expf(-z));
}
// swizzled bf16 store into a [rows][128] activation tile (16B-chunk xor-swizzle, r&15)
static __device__ __forceinline__ void stA(unsigned short* dst, int r, int c, float v) {
    dst[(r << 7) + (((c >> 3) ^ (r & 15)) << 3) + (c & 7)] = f2bf(v);
}
// swizzled element index into a [32][256] bf16 tile
static __device__ __forceinline__ int idxG(int r, int c) {
    return (r << 8) + (((c >> 3) ^ (r & 15)) << 3) + (c & 7);
}

#define MFMA(a, bfr, acc) __builtin_amdgcn_mfma_f32_16x16x32_bf16((a), (bfr), (acc), 0, 0, 0)

// ---------------- prep: fp32 weights -> padded bf16 in ws; zero hidden accum ----
__global__ __launch_bounds__(256) void prep_kernel(
    const float* __restrict__ wx, const float* __restrict__ wm1,
    const float* __restrict__ wm2, const float* __restrict__ wm3,
    const float* __restrict__ wm4, const float* __restrict__ wm5,
    unsigned short* __restrict__ wb, float* __restrict__ hid)
{
    const int stride = gridDim.x * blockDim.x;
    for (int idx = blockIdx.x * blockDim.x + threadIdx.x; idx < W_TOTAL; idx += stride) {
        float v;
        if (idx < OFF_W1) {
            v = wx[idx];                                      // exact 256x512
        } else if (idx < OFF_W2) {
            int j = idx - OFF_W1; int n = j >> 9, k = j & 511;
            v = (n < 100) ? wm1[n * 512 + k] : 0.f;
        } else if (idx < OFF_W3) {
            int j = idx - OFF_W2; int n = j >> 7, k = j & 127;
            v = (n < 100 && k < 100) ? wm2[n * 100 + k] : 0.f;
        } else if (idx < OFF_W4) {
            int j = idx - OFF_W3; int n = j >> 7, k = j & 127;
            v = (n < 100 && k < 100) ? wm3[n * 100 + k] : 0.f;
        } else if (idx < OFF_W5) {
            int j = idx - OFF_W4; int n = j >> 7, k = j & 127;
            v = (n < 50 && k < 100) ? wm4[n * 100 + k] : 0.f;
        } else {
            int j = idx - OFF_W5; int n = j >> 6, k = j & 63;
            v = (k < 50) ? wm5[n * 50 + k] : 0.f;
        }
        wb[idx] = f2bf(v);
    }
    for (int idx = blockIdx.x * blockDim.x + threadIdx.x; idx < 65536; idx += stride)
        hid[idx] = 0.f;
}

// ---------------- main fused kernel ---------------------------------------------
// block = (batch b, 32 timesteps). 512 threads = 8 waves, N-split across waves.
// __launch_bounds__(512, 4): 128 unified regs/wave -> room for an explicit 2-deep
// B-fragment ping-pong in pass 1 (the kernel was register-starved out of load
// pipelining at (512,8): VGPR_Count 32, each k-step serially ate L2 latency).
// Occupancy drops to ~50% — proven perf-neutral here (r0 46% == r3 92%).
__global__ __launch_bounds__(512, 4) void srnn_main(
    const float* __restrict__ x,
    const float* __restrict__ b1, const float* __restrict__ b2,
    const float* __restrict__ b3, const float* __restrict__ b4,
    const float* __restrict__ b5, const float* __restrict__ bx,
    const unsigned short* __restrict__ wb, float* __restrict__ hid)
{
    __shared__ __align__(16) unsigned short Xs[TR * 512];   // swizzled x tile (32 KB)
    __shared__ __align__(16) unsigned short A1[TR * 128];   // swizzled act tile (8 KB)
    unsigned short* A2  = Xs;          // [32][128] swizzled, aliases Xs[0..8KB) after pass 1
    unsigned short* Lxs = Xs + 4096;   // [32][256] swizzled, aliases Xs[8..24KB): sig(lx), then gate

    const int tid  = threadIdx.x;
    const int w    = tid >> 6, lane = tid & 63;
    const int blk  = blockIdx.x;
    const int b    = blk >> 4;
    const int t0   = (blk & 15) << 5;
    const int l15  = lane & 15;
    const int rb   = (lane >> 4) << 2;
    const int kp   = (lane >> 4) << 3;

    // ---- stage x tile: 512 threads x 8 float4 HBM loads, convert + swizzled store
    {
        const int m0 = tid >> 7;               // 0..3
        const int c4 = tid & 127;
        const float* xbase = x + ((size_t)(t0 + m0) * 256 + b) * 512 + (c4 << 2);
        float4 xr[8];
#pragma unroll
        for (int it = 0; it < 8; it++)
            xr[it] = *(const float4*)(xbase + (size_t)it * 524288);   // 4 timesteps apart
        const int blk8 = c4 >> 1, halfoff = (c4 & 1) << 2;
#pragma unroll
        for (int it = 0; it < 8; it++) {
            const int m = m0 + 4 * it;
            unsigned int p0 = (unsigned int)f2bf(xr[it].x) | ((unsigned int)f2bf(xr[it].y) << 16);
            unsigned int p1 = (unsigned int)f2bf(xr[it].z) | ((unsigned int)f2bf(xr[it].w) << 16);
            *(uint2*)&Xs[(m << 9) + ((blk8 ^ (m & 15)) << 3) + halfoff] = make_uint2(p0, p1);
        }
    }
    __syncthreads();

    // ---- fused pass 1: m1 (1 n-tile) + lx (2 n-tiles) per wave, K=512
    //      explicit 2-deep software pipeline on the 3 weight streams
    f32x4 am1[2], alx[2][2];
    am1[0] = {0,0,0,0}; am1[1] = {0,0,0,0};
#pragma unroll
    for (int i = 0; i < 2; i++) { alx[i][0] = {0,0,0,0}; alx[i][1] = {0,0,0,0}; }
    {
        const unsigned short* W1r  = wb + OFF_W1 + (w * 16 + l15) * 512 + kp;
        const unsigned short* WXr0 = wb + OFF_WX + (w * 16 + l15) * 512 + kp;
        const unsigned short* WXr1 = wb + OFF_WX + ((w + 8) * 16 + l15) * 512 + kp;
        const unsigned short* Xr0  = Xs + (l15 << 9);
        const unsigned short* Xr1  = Xs + ((16 + l15) << 9);
        const int klo = lane >> 4;

        short8 pA0 = *(const short8*)(W1r);            // k0 = 0 fragments
        short8 pA1 = *(const short8*)(WXr0);
        short8 pA2 = *(const short8*)(WXr1);
        short8 pB0, pB1, pB2;

#pragma unroll
        for (int k0 = 0; k0 < 512; k0 += 64) {
            // prefetch k0+32 weight frags (land under this half's MFMAs)
            pB0 = *(const short8*)(W1r  + k0 + 32);
            pB1 = *(const short8*)(WXr0 + k0 + 32);
            pB2 = *(const short8*)(WXr1 + k0 + 32);
            {
                const int kb = (k0 >> 3) + klo;
                const int xo = (kb ^ l15) << 3;
                short8 af0 = *(const short8*)(Xr0 + xo);
                short8 af1 = *(const short8*)(Xr1 + xo);
                am1[0]    = MFMA(af0, pA0, am1[0]);
                am1[1]    = MFMA(af1, pA0, am1[1]);
                alx[0][0] = MFMA(af0, pA1, alx[0][0]);
                alx[0][1] = MFMA(af1, pA1, alx[0][1]);
                alx[1][0] = MFMA(af0, pA2, alx[1][0]);
                alx[1][1] = MFMA(af1, pA2, alx[1][1]);
            }
            // prefetch k0+64 weight frags (compile-time guard; unrolled loop)
            if (k0 + 64 < 512) {
                pA0 = *(const short8*)(W1r  + k0 + 64);
                pA1 = *(const short8*)(WXr0 + k0 + 64);
                pA2 = *(const short8*)(WXr1 + k0 + 64);
            }
            {
                const int kb = ((k0 + 32) >> 3) + klo;
                const int xo = (kb ^ l15) << 3;
                short8 af0 = *(const short8*)(Xr0 + xo);
                short8 af1 = *(const short8*)(Xr1 + xo);
                am1[0]    = MFMA(af0, pB0, am1[0]);
                am1[1]    = MFMA(af1, pB0, am1[1]);
                alx[0][0] = MFMA(af0, pB1, alx[0][0]);
                alx[0][1] = MFMA(af1, pB1, alx[0][1]);
                alx[1][0] = MFMA(af0, pB2, alx[1][0]);
                alx[1][1] = MFMA(af1, pB2, alx[1][1]);
            }
        }
        // epilogue m1 -> A1 (relu)
        const int c = w * 16 + l15;
        const bool ok = (c < 100);
        const float bb = ok ? b1[c] : 0.f;
#pragma unroll
        for (int mt = 0; mt < 2; mt++)
#pragma unroll
            for (int q = 0; q < 4; q++)
                stA(A1, mt * 16 + rb + q, c, ok ? fmaxf(am1[mt][q] + bb, 0.f) : 0.f);
    }
    __syncthreads();

    // ---- dump sigmoid(lx + bx) -> Lxs (bf16); alx registers die HERE
    {
#pragma unroll
        for (int i = 0; i < 2; i++) {
            const int c = (w + 8 * i) * 16 + l15;
            const float bbx = bx[c];
#pragma unroll
            for (int mt = 0; mt < 2; mt++)
#pragma unroll
                for (int q = 0; q < 4; q++) {
                    const int r = mt * 16 + rb + q;
                    Lxs[idxG(r, c)] = f2bf(sigf(alx[i][mt][q] + bbx));
                }
        }
    }

    // ---- m2 / m3: one n-tile per wave, K=128
    auto stage23 = [&](const unsigned short* As, const unsigned short* Wg,
                       const float* __restrict__ bias, unsigned short* Ad) {
        f32x4 acc[2];
        acc[0] = {0,0,0,0}; acc[1] = {0,0,0,0};
        const unsigned short* Wr = Wg + (w * 16 + l15) * 128 + kp;
#pragma unroll
        for (int k0 = 0; k0 < 128; k0 += 32) {
            const int kb = (k0 >> 3) + (lane >> 4);
            const int xo = (kb ^ l15) << 3;
            short8 af0 = *(const short8*)(As + (l15 << 7) + xo);
            short8 af1 = *(const short8*)(As + ((16 + l15) << 7) + xo);
            short8 bf  = *(const short8*)(Wr + k0);
            acc[0] = MFMA(af0, bf, acc[0]);
            acc[1] = MFMA(af1, bf, acc[1]);
        }
        const int c = w * 16 + l15;
        const bool ok = (c < 100);
        const float bb = ok ? bias[c] : 0.f;
#pragma unroll
        for (int mt = 0; mt < 2; mt++)
#pragma unroll
            for (int q = 0; q < 4; q++)
                stA(Ad, mt * 16 + rb + q, c, ok ? fmaxf(acc[mt][q] + bb, 0.f) : 0.f);
    };
    stage23(A1, wb + OFF_W2, b2, A2);     // writes Xs[0..8KB), disjoint from Lxs
    __syncthreads();
    stage23(A2, wb + OFF_W3, b3, A1);
    __syncthreads();

    // ---- m4: (n-tile, m-tile) = (w>>1, w&1), K=128, 64 cols (real 50)
    {
        const int nt = w >> 1, mtl = w & 1;
        f32x4 acc = {0,0,0,0};
        const unsigned short* Wr = wb + OFF_W4 + (nt * 16 + l15) * 128 + kp;
        const int rbase = mtl * 16 + l15;
        const int rxo = rbase & 15;                            // == l15
#pragma unroll
        for (int k0 = 0; k0 < 128; k0 += 32) {
            const int kb = (k0 >> 3) + (lane >> 4);
            short8 af = *(const short8*)(A1 + (rbase << 7) + ((kb ^ rxo) << 3));
            short8 bf = *(const short8*)(Wr + k0);
            acc = MFMA(af, bf, acc);
        }
        const int c = nt * 16 + l15;
        const bool ok = (c < 50);
        const float bb = ok ? b4[c] : 0.f;
#pragma unroll
        for (int q = 0; q < 4; q++)
            stA(A2, mtl * 16 + rb + q, c, ok ? fmaxf(acc[q] + bb, 0.f) : 0.f);
    }
    __syncthreads();

    // ---- m5 (K=64): n-tiles {w, w+8}; gate = sig(m5)*Lxs, written in place
    {
        f32x4 a5[2][2];
#pragma unroll
        for (int i = 0; i < 2; i++) { a5[i][0] = {0,0,0,0}; a5[i][1] = {0,0,0,0}; }
        const unsigned short* W5r0 = wb + OFF_W5 + (w * 16 + l15) * 64 + kp;
        const unsigned short* W5r1 = wb + OFF_W5 + ((w + 8) * 16 + l15) * 64 + kp;
#pragma unroll
        for (int k0 = 0; k0 < 64; k0 += 32) {
            const int kb = (k0 >> 3) + (lane >> 4);
            const int xo = (kb ^ l15) << 3;
            short8 af0 = *(const short8*)(A2 + (l15 << 7) + xo);
            short8 af1 = *(const short8*)(A2 + ((16 + l15) << 7) + xo);
            short8 bf0 = *(const short8*)(W5r0 + k0);
            short8 bf1 = *(const short8*)(W5r1 + k0);
            a5[0][0] = MFMA(af0, bf0, a5[0][0]);
            a5[0][1] = MFMA(af1, bf0, a5[0][1]);
            a5[1][0] = MFMA(af0, bf1, a5[1][0]);
            a5[1][1] = MFMA(af1, bf1, a5[1][1]);
        }
#pragma unroll
        for (int i = 0; i < 2; i++) {
            const int c = (w + 8 * i) * 16 + l15;
            const float bb5 = b5[c];
#pragma unroll
            for (int mt = 0; mt < 2; mt++)
#pragma unroll
                for (int q = 0; q < 4; q++) {
                    const int r = mt * 16 + rb + q;
                    const int ix = idxG(r, c);
                    const float g = sigf(a5[i][mt][q] + bb5) * bf2f(Lxs[ix]);
                    Lxs[ix] = f2bf(g);     // each (r,c) owned by exactly one lane
                }
        }
    }
    __syncthreads();

    // ---- rotated reduction: hidden[b][j] += sum_m gate[t0+m][b][(j+t0+m+1)&255]
    {
        const int j    = tid & 255;
        const int half = tid >> 8;             // 0,1 -> rows 0..15 / 16..31
        const int base = (j + t0 + 1) & 255;
        float ph = 0.f;
#pragma unroll
        for (int mm = 0; mm < 16; mm++) {
            const int m  = half * 16 + mm;
            const int cm = (base + m) & 255;
            ph += bf2f(Lxs[idxG(m, cm)]);
        }
        atomicAdd(hid + b * 256 + j, ph);
    }
}

// ---------------- output: out = hidden @ wo^T + bo ; also emit hidden ----------
__global__ __launch_bounds__(256) void out_kernel(
    const float* __restrict__ hid, const float* __restrict__ wo,
    const float* __restrict__ bo, float* __restrict__ out)
{
    __shared__ __align__(16) float hrow[256];
    const int b = blockIdx.x, o = threadIdx.x;
    float h = hid[b * 256 + o];
    hrow[o] = h;
    out[65536 + b * 256 + o] = h;          // second output: hidden
    __syncthreads();
    const float4* wrow = (const float4*)(wo + o * 256);
    float s = bo[o];
#pragma unroll 8
    for (int k4 = 0; k4 < 64; k4++) {
        float4 w = wrow[k4];
        float4 hh = *(const float4*)&hrow[k4 * 4];
        s += hh.x * w.x + hh.y * w.y + hh.z * w.z + hh.w * w.w;
    }
    out[b * 256 + o] = s;
}

extern "C" void kernel_launch(void* const* d_in, const int* in_sizes, int n_in,
                              void* d_out, int out_size, void* d_ws, size_t ws_size,
                              hipStream_t stream)
{
    (void)in_sizes; (void)n_in; (void)out_size; (void)ws_size;
    const float* x   = (const float*)d_in[0];
    const float* wm1 = (const float*)d_in[1];
    const float* bm1 = (const float*)d_in[2];
    const float* wm2 = (const float*)d_in[3];
    const float* bm2 = (const float*)d_in[4];
    const float* wm3 = (const float*)d_in[5];
    const float* bm3 = (const float*)d_in[6];
    const float* wm4 = (const float*)d_in[7];
    const float* bm4 = (const float*)d_in[8];
    const float* wm5 = (const float*)d_in[9];
    const float* bm5 = (const float*)d_in[10];
    const float* wx  = (const float*)d_in[11];
    const float* bx  = (const float*)d_in[12];
    const float* wo  = (const float*)d_in[13];
    const float* bo  = (const float*)d_in[14];
    float* out = (float*)d_out;

    unsigned short* wb = (unsigned short*)d_ws;
    float* hid = (float*)((char*)d_ws + (size_t)W_TOTAL * 2);   // fp32 hidden accumulator

    prep_kernel<<<512, 256, 0, stream>>>(wx, wm1, wm2, wm3, wm4, wm5, wb, hid);
    srnn_main<<<4096, 512, 0, stream>>>(x, bm1, bm2, bm3, bm4, bm5, bx, wb, hid);
    out_kernel<<<256, 256, 0, stream>>>(hid, wo, bo, out);
}